// Round 6
// baseline (178.479 us; speedup 1.0000x reference)
//
#include <hip/hip_runtime.h>
#include <cstdint>
#include <cstddef>

// DeformablePoseViT: bs=16, lq=1000, d=256, nh=8, L=4, P=4, dh=32
// value pyramid: (80,80),(40,40),(20,20),(10,10) -> lv=8500
//
// Pipeline:
//  0) wconv          : Wt_* = bf16(W_*^T) [N][256]; Wt_qkv = [W_off|W_attn]
//  1) gemm_bres<true>: vbf = bf16(value @ W_val + b_val)   [136000x256]
//  2) gemm_bres<false>: Lg = query @ [W_off|W_attn] + b    [16000x384]
//  3) sample_fused   : softmax+locs (in-block) + bilinear gather -> outs
//  4) gemm_bres<false>: d_out = outs @ W_out + b_out       [16000x256]
//
// gemm_bres: B-resident streaming GEMM. B tile (128 cols x 256 k, bf16,
// 64KB) preloaded once into LDS via global_load_lds with XOR-swizzle.
// A rows stream global->VGPR (wave-private rows, 2-deep reg prefetch),
// f32->bf16 in-register, MFMA 16x16x32. NO barriers in the K loop ->
// waves free-run, HBM latency hidden by TLP+ILP.

typedef unsigned short u16;
typedef u16 u16x8 __attribute__((ext_vector_type(8)));
typedef __bf16 bf16x8 __attribute__((ext_vector_type(8)));
typedef float f32x4 __attribute__((ext_vector_type(4)));

__device__ inline u16 f2bf(float f) {
  return __builtin_bit_cast(u16, (__bf16)f);
}

__device__ __forceinline__ void glds16(const void* g, void* l) {
  __builtin_amdgcn_global_load_lds(
      (const __attribute__((address_space(1))) void*)g,
      (__attribute__((address_space(3))) void*)l, 16, 0, 0);
}

// ---------------------------------------------------------------------------
// Weight prep: Wt[n][k] = bf16(W[k][n]). K=256 for all 4 matrices.
// grid (4,4,4): x->n-tile, y->k-tile, z->matrix. Also builds combined bias.
__global__ __launch_bounds__(256) void wconv(
    const float* __restrict__ W0, const float* __restrict__ W1,
    const float* __restrict__ W2, const float* __restrict__ W3,
    u16* __restrict__ T0, u16* __restrict__ T1, u16* __restrict__ T2,
    u16* __restrict__ T3, const float* __restrict__ b_off,
    const float* __restrict__ b_attn, float* __restrict__ cbias) {
  __shared__ u16 tile[64][65];
  const float* Ws[4] = {W0, W1, W2, W3};
  u16* Ts[4] = {T0, T1, T2, T3};
  const int Ns[4] = {256, 256, 128, 256};
  const int z = blockIdx.z;
  const int N = Ns[z];
  const int n0 = blockIdx.x * 64;
  if (blockIdx.x == 0 && blockIdx.y == 0) {
    if (z == 1) cbias[threadIdx.x] = b_off[threadIdx.x];
    if (z == 2 && threadIdx.x < 128) cbias[256 + threadIdx.x] = b_attn[threadIdx.x];
  }
  if (n0 >= N) return;
  const int k0 = blockIdx.y * 64;
  const float* W = Ws[z];
  u16* Wt = Ts[z];
  const int tr = threadIdx.x >> 6;   // 0..3
  const int tc = threadIdx.x & 63;
#pragma unroll
  for (int r = 0; r < 64; r += 4)
    tile[r + tr][tc] = f2bf(W[(size_t)(k0 + r + tr) * N + n0 + tc]);
  __syncthreads();
#pragma unroll
  for (int r = 0; r < 64; r += 4)
    Wt[(size_t)(n0 + r + tr) * 256 + k0 + tc] = tile[tc][r + tr];
}

// ---------------------------------------------------------------------------
// C[M,N] = A[M,256]f32 (cast bf16) @ Wt[N,256]bf16^T + bias[N]
// 256 threads = 4 waves, wave tile 32x128 (2x8 16x16 frags, wave-private A).
// LDS: Bls[col][k] bf16, 128x256 = 64KB, 16B-chunk XOR swizzle
//   physical_chunk = logical_chunk ^ (col & 7)  ->  8 lanes/bank-quad reads.
template <bool OUT_BF16>
__global__ __launch_bounds__(256) void gemm_bres(
    const float* __restrict__ A, const u16* __restrict__ Wt,
    const float* __restrict__ bias, void* __restrict__ Cv, int M, int N) {
  __shared__ __align__(16) u16 Bls[128 * 256];  // 64KB
  const int t = threadIdx.x;
  const int m0 = blockIdx.x * 128;
  const int n0 = blockIdx.y * 128;
  const int wave = t >> 6;
  const int lane = t & 63;
  const int lr = lane & 15;
  const int kof = (lane >> 4) * 8;  // k-element offset of this lane's frag

  // ---- B preload: 64 glds16 insts, each fills 1KB (= 2 swizzled cols) ----
#pragma unroll
  for (int g = 0; g < 16; ++g) {
    int inst = wave * 16 + g;
    int col = inst * 2 + (lane >> 5);
    int p = lane & 31;                 // physical 16B chunk within col row
    int j = p ^ (col & 7);             // logical chunk (k-window) at p
    glds16((const char*)Wt + (size_t)(n0 + col) * 512 + j * 16,
           (char*)Bls + inst * 1024);
  }

  // A row pointers (wave-private rows; clamp tail)
  const float* aptr[2];
#pragma unroll
  for (int mi = 0; mi < 2; ++mi) {
    int gr = m0 + wave * 32 + mi * 16 + lr;
    if (gr > M - 1) gr = M - 1;
    aptr[mi] = A + (size_t)gr * 256 + kof;
  }

  f32x4 acc[2][8] = {};

  auto loadA = [&](f32x4 (&buf)[2][2][2], int tk) {
#pragma unroll
    for (int mi = 0; mi < 2; ++mi)
#pragma unroll
      for (int kk = 0; kk < 2; ++kk) {
        const float* p = aptr[mi] + tk * 64 + kk * 32;
        buf[mi][kk][0] = *(const f32x4*)p;
        buf[mi][kk][1] = *(const f32x4*)(p + 4);
      }
  };
  auto computeT = [&](const f32x4 (&buf)[2][2][2], int tk) {
#pragma unroll
    for (int kk = 0; kk < 2; ++kk) {
      bf16x8 af[2];
#pragma unroll
      for (int mi = 0; mi < 2; ++mi) {
        bf16x8 v;
        v[0] = (__bf16)buf[mi][kk][0][0];
        v[1] = (__bf16)buf[mi][kk][0][1];
        v[2] = (__bf16)buf[mi][kk][0][2];
        v[3] = (__bf16)buf[mi][kk][0][3];
        v[4] = (__bf16)buf[mi][kk][1][0];
        v[5] = (__bf16)buf[mi][kk][1][1];
        v[6] = (__bf16)buf[mi][kk][1][2];
        v[7] = (__bf16)buf[mi][kk][1][3];
        af[mi] = v;
      }
      const int j = tk * 8 + kk * 4 + (lane >> 4);  // logical chunk
#pragma unroll
      for (int ni = 0; ni < 8; ++ni) {
        int col = ni * 16 + lr;
        int p = j ^ (lr & 7);
        bf16x8 b = __builtin_bit_cast(
            bf16x8, *(const u16x8*)((const char*)Bls + col * 512 + p * 16));
        acc[0][ni] = __builtin_amdgcn_mfma_f32_16x16x32_bf16(
            af[0], b, acc[0][ni], 0, 0, 0);
        acc[1][ni] = __builtin_amdgcn_mfma_f32_16x16x32_bf16(
            af[1], b, acc[1][ni], 0, 0, 0);
      }
    }
  };

  // prefetch 2 tiles of A into regs while B preload is in flight
  f32x4 ar0[2][2][2], ar1[2][2][2];
  loadA(ar0, 0);
  loadA(ar1, 1);
  __syncthreads();  // B preload complete (drains vmcnt; A regs also done)
  computeT(ar0, 0);
  loadA(ar0, 2);
  computeT(ar1, 1);
  loadA(ar1, 3);
  computeT(ar0, 2);
  computeT(ar1, 3);

  // epilogue: C frag layout col=lane&15, row=(lane>>4)*4+r
  float bv[8];
#pragma unroll
  for (int ni = 0; ni < 8; ++ni) bv[ni] = bias[n0 + ni * 16 + lr];
  const int rit = (lane >> 4) * 4;
#pragma unroll
  for (int mi = 0; mi < 2; ++mi) {
#pragma unroll
    for (int r = 0; r < 4; ++r) {
      int grow = m0 + wave * 32 + mi * 16 + rit + r;
      if (grow >= M) continue;
#pragma unroll
      for (int ni = 0; ni < 8; ++ni) {
        int gcol = n0 + ni * 16 + lr;
        float v = acc[mi][ni][r] + bv[ni];
        if (OUT_BF16)
          ((u16*)Cv)[(size_t)grow * N + gcol] = f2bf(v);
        else
          ((float*)Cv)[(size_t)grow * N + gcol] = v;
      }
    }
  }
}

// ---------------------------------------------------------------------------
// Fused qpost+sample: 8 queries/block. Phase 1: stage bbox + attn logits.
// Phase 2: compute pixel locs (sl) + softmax (sa). Phase 3: bilinear gather.
// 256 threads in gather = ql*32 + (h*4 + cg).
__global__ __launch_bounds__(256) void sample_fused(
    const float* __restrict__ Lg, const float* __restrict__ bbox,
    const u16* __restrict__ vbf, float* __restrict__ outs) {
  const int blk = blockIdx.x;
  const int i0 = blk * 8;
  const int t = threadIdx.x;
  __shared__ __align__(16) float sl[8 * 256];
  __shared__ __align__(16) float sa[8 * 128];
  __shared__ float sb[32];
  if (t < 32) sb[t] = bbox[(size_t)i0 * 4 + t];
#pragma unroll
  for (int j = 0; j < 4; ++j) {
    int idx = j * 256 + t;
    int ql = idx >> 7, c = idx & 127;
    sa[idx] = Lg[(size_t)(i0 + ql) * 384 + 256 + c];
  }
  __syncthreads();
  // pixel-space locations from offset logits
#pragma unroll
  for (int j = 0; j < 8; ++j) {
    int idx = j * 256 + t;
    int ql = idx >> 8, e = idx & 255;
    float off = Lg[(size_t)(i0 + ql) * 384 + e];
    int l = (e >> 3) & 3, xy = e & 1;
    float c = sb[ql * 4 + xy], wh = sb[ql * 4 + 2 + xy];
    sl[idx] = (c + off * 0.125f * wh) * (float)(80 >> l) - 0.5f;
  }
  // softmax over 16 per (query, head): threads 0..63
  if (t < 64) {
    int base = (t >> 3) * 128 + (t & 7) * 16;
    float mx = -3.0e38f;
#pragma unroll
    for (int j = 0; j < 16; ++j) mx = fmaxf(mx, sa[base + j]);
    float e[16];
    float s = 0.f;
#pragma unroll
    for (int j = 0; j < 16; ++j) {
      e[j] = __expf(sa[base + j] - mx);
      s += e[j];
    }
    float inv = 1.f / s;
#pragma unroll
    for (int j = 0; j < 16; ++j) sa[base + j] = e[j] * inv;
  }
  __syncthreads();

  const int ql = t >> 5;
  const int r = t & 31;
  const int h = r >> 2;
  const int cg = r & 3;
  const int choff = h * 32 + cg * 8;
  const int i = i0 + ql;
  const int b = blk / 125;
  const u16* vb = vbf + (size_t)b * 8500 * 256;

  float acc[8] = {};
  const int baseL[4] = {0, 6400, 8000, 8400};
  const int dimL[4] = {80, 40, 20, 10};

#pragma unroll
  for (int l = 0; l < 4; ++l) {
    const int W = dimL[l];
    const u16* vl = vb + (size_t)baseL[l] * 256 + choff;
#pragma unroll
    for (int p = 0; p < 4; ++p) {
      float x = sl[ql * 256 + h * 32 + l * 8 + p * 2 + 0];
      float y = sl[ql * 256 + h * 32 + l * 8 + p * 2 + 1];
      float aw = sa[ql * 128 + h * 16 + l * 4 + p];
      float x0f = floorf(x), y0f = floorf(y);
      float wx = x - x0f, wy = y - y0f;
      int x0 = (int)x0f, y0 = (int)y0f;
      int x1 = x0 + 1, y1 = y0 + 1;
      float fx0 = (x0 >= 0 && x0 < W) ? 1.f : 0.f;
      float fx1 = (x1 >= 0 && x1 < W) ? 1.f : 0.f;
      float fy0 = (y0 >= 0 && y0 < W) ? 1.f : 0.f;
      float fy1 = (y1 >= 0 && y1 < W) ? 1.f : 0.f;
      int xc0 = min(max(x0, 0), W - 1), xc1 = min(max(x1, 0), W - 1);
      int yc0 = min(max(y0, 0), W - 1), yc1 = min(max(y1, 0), W - 1);
      float w00 = aw * (1.f - wx) * (1.f - wy) * fx0 * fy0;
      float w01 = aw * wx * (1.f - wy) * fx1 * fy0;
      float w10 = aw * (1.f - wx) * wy * fx0 * fy1;
      float w11 = aw * wx * wy * fx1 * fy1;
      uint4 v00 = *(const uint4*)(vl + (size_t)(yc0 * W + xc0) * 256);
      uint4 v01 = *(const uint4*)(vl + (size_t)(yc0 * W + xc1) * 256);
      uint4 v10 = *(const uint4*)(vl + (size_t)(yc1 * W + xc0) * 256);
      uint4 v11 = *(const uint4*)(vl + (size_t)(yc1 * W + xc1) * 256);
      const uint32_t* p00 = (const uint32_t*)&v00;
      const uint32_t* p01 = (const uint32_t*)&v01;
      const uint32_t* p10 = (const uint32_t*)&v10;
      const uint32_t* p11 = (const uint32_t*)&v11;
#pragma unroll
      for (int k = 0; k < 4; ++k) {
        float a0 = __uint_as_float(p00[k] << 16);
        float a1 = __uint_as_float(p00[k] & 0xffff0000u);
        float b0 = __uint_as_float(p01[k] << 16);
        float b1 = __uint_as_float(p01[k] & 0xffff0000u);
        float c0 = __uint_as_float(p10[k] << 16);
        float c1 = __uint_as_float(p10[k] & 0xffff0000u);
        float d0 = __uint_as_float(p11[k] << 16);
        float d1 = __uint_as_float(p11[k] & 0xffff0000u);
        acc[2 * k] += w00 * a0 + w01 * b0 + w10 * c0 + w11 * d0;
        acc[2 * k + 1] += w00 * a1 + w01 * b1 + w10 * c1 + w11 * d1;
      }
    }
  }
  float4* op = (float4*)(outs + (size_t)i * 256 + choff);
  op[0] = make_float4(acc[0], acc[1], acc[2], acc[3]);
  op[1] = make_float4(acc[4], acc[5], acc[6], acc[7]);
}

extern "C" void kernel_launch(void* const* d_in, const int* in_sizes, int n_in,
                              void* d_out, int out_size, void* d_ws, size_t ws_size,
                              hipStream_t stream) {
  const float* query  = (const float*)d_in[0];
  const float* bbox   = (const float*)d_in[1];
  const float* value  = (const float*)d_in[2];
  const float* W_off  = (const float*)d_in[3];
  const float* b_off  = (const float*)d_in[4];
  const float* W_attn = (const float*)d_in[5];
  const float* b_attn = (const float*)d_in[6];
  const float* W_val  = (const float*)d_in[7];
  const float* b_val  = (const float*)d_in[8];
  const float* W_out  = (const float*)d_in[9];
  const float* b_out  = (const float*)d_in[10];
  float* out = (float*)d_out;

  // workspace layout
  char* w = (char*)d_ws;
  u16* vbf     = (u16*)w;                    // 69,632,000 B
  float* Lg    = (float*)(w + 69632000);     // 16000*384*4 = 24,576,000 B
  float* outs  = (float*)(w + 94208000);     // 16000*256*4 = 16,384,000 B
  u16* Wt_val  = (u16*)(w + 110592000);      //    131,072 B
  u16* Wt_qkv  = (u16*)(w + 110723072);      //    196,608 B (384x256)
  u16* Wt_out  = (u16*)(w + 110919680);      //    131,072 B
  float* cbias = (float*)(w + 111050752);    //      1,536 B

  const int M_v = 16 * 8500;  // 136000
  const int M_q = 16 * 1000;  // 16000

  // 0) weight prep (bf16 transpose + combined qkv weights/bias)
  wconv<<<dim3(4, 4, 4), 256, 0, stream>>>(
      W_val, W_off, W_attn, W_out, Wt_val, Wt_qkv, Wt_qkv + 256 * 256, Wt_out,
      b_off, b_attn, cbias);
  // 1) value projection -> bf16
  gemm_bres<true><<<dim3((M_v + 127) / 128, 2), 256, 0, stream>>>(
      value, Wt_val, b_val, (void*)vbf, M_v, 256);
  // 2) combined offset+attn logits [16000x384]
  gemm_bres<false><<<dim3(M_q / 128, 3), 256, 0, stream>>>(
      query, Wt_qkv, cbias, (void*)Lg, M_q, 384);
  // 3) fused softmax/locs + bilinear sampling
  sample_fused<<<2000, 256, 0, stream>>>(Lg, bbox, vbf, outs);
  // 4) output projection
  gemm_bres<false><<<dim3(M_q / 128, 2), 256, 0, stream>>>(
      outs, Wt_out, b_out, (void*)out, M_q, 256);
}